// Round 3
// baseline (561.112 us; speedup 1.0000x reference)
//
#include <hip/hip_runtime.h>
#include <math.h>

#define B 256
#define F 512
#define C 100000
#define S_SCALE 64.0f
#define M_MARGIN 0.4f
#define K_VP 0.7f

#define BN 64
#define NTILES ((C + BN - 1) / BN)   // 1563 (last tile has 32 valid cols)
#define NT_TOT (2 * NTILES)          // 3126 flat tiles (src0: weight, src1: queue)
#define NBLK 256                     // persistent blocks, 1 per CU

typedef __bf16 bf16x8 __attribute__((ext_vector_type(8)));
typedef float  floatx4 __attribute__((ext_vector_type(4)));

// ---------- fused: emb = l2norm(input) -> swizzled bf16 A + newrows (exact fp32) ----------
// embb_sw layout: A-frag for (rowtile R, kstep ks) at 1KB region ((R*16+ks)*64 + lane)*16B,
// lane = (row&15) + 16*q, element j: k = ks*32 + q*8 + j.
__global__ void embnew_kernel(const float* __restrict__ input, const float* __restrict__ queue,
                              const int* __restrict__ label,
                              __bf16* __restrict__ embb_sw, float* __restrict__ newrows) {
    int i = blockIdx.x;
    int t = threadIdx.x;
    const float* x = input + (size_t)i * F;
    float x0 = x[t], x1 = x[t + 256];
    float p = x0 * x0 + x1 * x1;
    __shared__ float red[4];
    for (int off = 32; off > 0; off >>= 1) p += __shfl_down(p, off, 64);
    if ((t & 63) == 0) red[t >> 6] = p;
    __syncthreads();
    float tot = red[0] + red[1] + red[2] + red[3];
    float inv = 1.0f / fmaxf(sqrtf(tot), 1e-5f);
    float e0 = x0 * inv, e1 = x1 * inv;
    {
        int R = i >> 4, ln = i & 15;
        int k = t;
        embb_sw[(size_t)(((R * 16 + (k >> 5)) * 64 + ln + 16 * ((k & 31) >> 3)) * 8 + (k & 7))] = (__bf16)e0;
        k = t + 256;
        embb_sw[(size_t)(((R * 16 + (k >> 5)) * 64 + ln + 16 * ((k & 31) >> 3)) * 8 + (k & 7))] = (__bf16)e1;
    }
    int l = label[i];
    const float* qr = queue + (size_t)l * F;
    float q0 = qr[t], q1 = qr[t + 256];
    float pd = q0 * e0 + q1 * e1;
    __syncthreads();
    for (int off = 32; off > 0; off >>= 1) pd += __shfl_down(pd, off, 64);
    if ((t & 63) == 0) red[t >> 6] = pd;
    __syncthreads();
    float drift = red[0] + red[1] + red[2] + red[3];
    float f = drift / (1.0f + fabsf(drift));   // softsign
    float v0 = f * q0 + (1.0f - f) * e0;
    float v1 = f * q1 + (1.0f - f) * e1;
    float p2 = v0 * v0 + v1 * v1;
    __syncthreads();
    for (int off = 32; off > 0; off >>= 1) p2 += __shfl_down(p2, off, 64);
    if ((t & 63) == 0) red[t >> 6] = p2;
    __syncthreads();
    float tot2 = red[0] + red[1] + red[2] + red[3];
    float inv2 = 1.0f / fmaxf(sqrtf(tot2), 1e-12f);
    newrows[(size_t)i * F + t]       = v0 * inv2;
    newrows[(size_t)i * F + t + 256] = v1 * inv2;
}

// ---------- map[c] = -1 ----------
__global__ void init_kernel(int* __restrict__ map) {
    int idx = blockIdx.x * 256 + threadIdx.x;
    if (idx < C) map[idx] = -1;
}

// ---------- last-occurrence-wins scatter (numpy queue[label]=rows semantics) ----------
__global__ void scatter_kernel(const int* __restrict__ label, int* __restrict__ map) {
    atomicMax(&map[label[threadIdx.x]], (int)threadIdx.x);
}

// ---------- persistent pipelined bf16 MFMA GEMM + EPL epilogue ----------
// 256 blocks x 512 threads, 1 block/CU (128KB double-buffered frag-region LDS).
// Per tile: W(ds_write staged regs) | barrier | colinv | ISSUE next-tile global loads |
// MFMA(current buf) | convert(loads->bf16+sumsq; vmcnt drains under MFMA cover) |
// barrier | epilogue. Next tile's HBM loads are in flight during the whole MFMA window
// (T14 async-STAGE split) -> memory pipe streams continuously toward the BW floor.
// LDS B layout per buffer: 64 x 1KB regions; region (ks*4+ct), slot=lane, lane-linear
// ds_write_b128/ds_read_b128 (conflict-free). Per-row negative partials via plain stores.
__global__ __launch_bounds__(512, 2) void gemm_epl_kernel(
        const __bf16* __restrict__ embb_sw,
        const float* __restrict__ weight,
        const float* __restrict__ queue,
        const float* __restrict__ newrows,
        const int* __restrict__ map,
        const int* __restrict__ label,
        float* __restrict__ partials,
        float* __restrict__ posvals) {
    int tid = threadIdx.x;
    int w = tid >> 6;          // 0..7
    int l = tid & 63;
    int ln = l & 15;
    int q = l >> 4;
    int ct = w & 3, h = w >> 2;
    int cl = ct * 16 + ln;     // column within tile owned by this thread (for staging)

    __shared__ __align__(16) __bf16 bS[2][64 * 512];   // 2 x 64 KB frag-region buffers
    __shared__ float colpart_s[BN][9];                  // padded
    __shared__ float colinv_s[BN];
    __shared__ int label_s[B];

    if (tid < B) label_s[tid] = label[tid];

    int ft0 = (int)(((long)blockIdx.x * NT_TOT) / NBLK);
    int ft1 = (int)(((long)(blockIdx.x + 1) * NT_TOT) / NBLK);

    float4 u[16];      // raw staged floats for NEXT tile (in flight during MFMA)
    bf16x8 sb[8];      // converted bf16 staged data for CURRENT tile
    float ss = 0.f;    // this thread's column sum-of-squares (current tile)

    // column base pointer for flat tile ft
    auto colptr = [&](int ft) -> const float* {
        int s1 = (ft >= NTILES);
        int tile = ft - s1 * NTILES;
        int c = tile * BN + cl;
        if (c >= C) return nullptr;
        if (!s1) return weight + (size_t)c * F;
        int mi = map[c];
        return (mi >= 0) ? newrows + (size_t)mi * F : queue + (size_t)c * F;
    };
    // issue 16 dwordx4 loads (no consumer -> stay in flight)
    auto issue_loads = [&](int ft) {
        const float* bp = colptr(ft);
#pragma unroll
        for (int j2 = 0; j2 < 8; ++j2) {
            int kf = (q + 4 * (h * 8 + j2)) * 8;   // 32B contiguous per lane
            if (bp) {
                u[2 * j2]     = *(const float4*)(bp + kf);
                u[2 * j2 + 1] = *(const float4*)(bp + kf + 4);
            } else {
                u[2 * j2]     = make_float4(0.f, 0.f, 0.f, 0.f);
                u[2 * j2 + 1] = make_float4(0.f, 0.f, 0.f, 0.f);
            }
        }
    };
    // fp32 -> bf16 + register sumsq (first use of u[]: vmcnt waits here)
    auto convert = [&]() {
        ss = 0.f;
#pragma unroll
        for (int j2 = 0; j2 < 8; ++j2) {
            float4 u0 = u[2 * j2], u1 = u[2 * j2 + 1];
            ss += u0.x * u0.x + u0.y * u0.y + u0.z * u0.z + u0.w * u0.w
                + u1.x * u1.x + u1.y * u1.y + u1.z * u1.z + u1.w * u1.w;
            bf16x8 bv;
            bv[0] = (__bf16)u0.x; bv[1] = (__bf16)u0.y; bv[2] = (__bf16)u0.z; bv[3] = (__bf16)u0.w;
            bv[4] = (__bf16)u1.x; bv[5] = (__bf16)u1.y; bv[6] = (__bf16)u1.z; bv[7] = (__bf16)u1.w;
            sb[j2] = bv;
        }
    };

    // prologue: stage first tile (not overlapped)
    issue_loads(ft0);
    convert();

    for (int ft = ft0; ft < ft1; ++ft) {
        int buf = ft & 1;
        int s1 = (ft >= NTILES);
        int tile = ft - s1 * NTILES;
        int c0 = tile * BN;

        // ---- W: lane-linear conflict-free ds_write of staged bf16 regs
#pragma unroll
        for (int j2 = 0; j2 < 8; ++j2) {
            int ks = h * 8 + j2;
            *(bf16x8*)&bS[buf][(((ks * 4 + ct) * 64 + l) * 8)] = sb[j2];
        }
        colpart_s[cl][h * 4 + q] = ss;
        __syncthreads();   // A: LDS[buf] + colpart ready (also orders label_s on first iter)

        if (tid < BN) {
            float ssum = 0.f;
#pragma unroll
            for (int p = 0; p < 8; ++p) ssum += colpart_s[tid][p];
            colinv_s[tid] = 1.0f / fmaxf(sqrtf(ssum), s1 ? 1e-12f : 1e-5f);
        }

        bool more = (ft + 1 < ft1);
        if (more) issue_loads(ft + 1);   // HBM loads fly under the MFMA window below

        // ---- M: MFMA main loop; wave w -> rows 32w..32w+31; depth-1 A-frag prefetch
        floatx4 acc[2][4];
#pragma unroll
        for (int rt = 0; rt < 2; ++rt)
#pragma unroll
            for (int c2 = 0; c2 < 4; ++c2) acc[rt][c2] = (floatx4){0.f, 0.f, 0.f, 0.f};

        bf16x8 af[2][2];
#pragma unroll
        for (int rt = 0; rt < 2; ++rt)
            af[0][rt] = *(const bf16x8*)(embb_sw + ((size_t)(((w * 2 + rt) * 16 + 0) * 64 + l) << 3));

#pragma unroll
        for (int ks = 0; ks < 16; ++ks) {
            if (ks < 15) {
#pragma unroll
                for (int rt = 0; rt < 2; ++rt)
                    af[(ks + 1) & 1][rt] =
                        *(const bf16x8*)(embb_sw + ((size_t)(((w * 2 + rt) * 16 + ks + 1) * 64 + l) << 3));
            }
            bf16x8 bfr[4];
#pragma unroll
            for (int c2 = 0; c2 < 4; ++c2)
                bfr[c2] = *(const bf16x8*)&bS[buf][(((ks * 4 + c2) * 64 + l) * 8)];
#pragma unroll
            for (int rt = 0; rt < 2; ++rt)
#pragma unroll
                for (int c2 = 0; c2 < 4; ++c2)
                    acc[rt][c2] = __builtin_amdgcn_mfma_f32_16x16x32_bf16(af[ks & 1][rt], bfr[c2], acc[rt][c2], 0, 0, 0);
        }

        if (more) convert();   // vmcnt drains here, covered by the MFMA above

        __syncthreads();   // B: colinv_s visible; LDS[buf] reads done

        // ---- E: epilogue: cos = acc * colinv; label col -> posvals; others -> partial
#pragma unroll
        for (int rt = 0; rt < 2; ++rt) {
#pragma unroll
            for (int r = 0; r < 4; ++r) {
                int row = (w * 2 + rt) * 16 + q * 4 + r;
                int lab = label_s[row];
                float sum = 0.f;
#pragma unroll
                for (int c2 = 0; c2 < 4; ++c2) {
                    int c = c0 + c2 * 16 + ln;
                    if (c < C) {
                        float cosv = acc[rt][c2][r] * colinv_s[c2 * 16 + ln];
                        if (c == lab) posvals[s1 * B + row] = cosv;  // unique writer per (src,row)
                        else sum += __expf(S_SCALE * cosv);
                    }
                }
                sum += __shfl_xor(sum, 1, 64);
                sum += __shfl_xor(sum, 2, 64);
                sum += __shfl_xor(sum, 4, 64);
                sum += __shfl_xor(sum, 8, 64);
                if (ln == 0) partials[(size_t)(s1 * B + row) * NTILES + tile] = sum;
            }
        }
    }
}

// ---------- reduce partials across tiles: negacc[row] = sum_t partials[row][t] ----------
__global__ void reduce_kernel(const float* __restrict__ partials, float* __restrict__ negacc) {
    int row = blockIdx.x;   // 0 .. 2B-1
    int t = threadIdx.x;    // 256
    float s = 0.f;
    for (int i = t; i < NTILES; i += 256) s += partials[(size_t)row * NTILES + i];
    __shared__ float red[4];
    for (int off = 32; off > 0; off >>= 1) s += __shfl_down(s, off, 64);
    if ((t & 63) == 0) red[t >> 6] = s;
    __syncthreads();
    if (t == 0) negacc[row] = red[0] + red[1] + red[2] + red[3];
}

// ---------- final EPL loss ----------
__global__ void loss_kernel(const float* __restrict__ negacc, const float* __restrict__ posvals,
                            float* __restrict__ out) {
    int t = threadIdx.x;  // 256
    float l1 = log1pf(negacc[t] * __expf(-S_SCALE * (posvals[t] - M_MARGIN)));
    float l2 = log1pf(negacc[B + t] * __expf(-S_SCALE * (1.0f - K_VP) * posvals[B + t]));
    float p = l1 + l2;
    __shared__ float red[4];
    for (int off = 32; off > 0; off >>= 1) p += __shfl_down(p, off, 64);
    if ((t & 63) == 0) red[t >> 6] = p;
    __syncthreads();
    if (t == 0) out[0] = (red[0] + red[1] + red[2] + red[3]) / (2.0f * B);
}

extern "C" void kernel_launch(void* const* d_in, const int* in_sizes, int n_in,
                              void* d_out, int out_size, void* d_ws, size_t ws_size,
                              hipStream_t stream) {
    const float* input  = (const float*)d_in[0];
    const float* weight = (const float*)d_in[1];
    const float* queue  = (const float*)d_in[2];
    const int*   label  = (const int*)d_in[3];
    float* out = (float*)d_out;

    char* ws = (char*)d_ws;
    __bf16* embb_sw  = (__bf16*)(ws);                         // 256 KB
    float*  newrows  = (float*)(ws + (256 << 10));            // 512 KB
    float*  negacc   = (float*)(ws + (768 << 10));            // 2 KB
    float*  posvals  = (float*)(ws + (768 << 10) + 2048);     // 2 KB
    int*    map      = (int*)  (ws + (768 << 10) + 4096);     // 400 KB
    float*  partials = (float*)(ws + (1200 << 10));           // 2B*NTILES*4 = 3.13 MB

    init_kernel<<<(C + 255) / 256, 256, 0, stream>>>(map);
    scatter_kernel<<<1, B, 0, stream>>>(label, map);
    embnew_kernel<<<B, 256, 0, stream>>>(input, queue, label, embb_sw, newrows);
    gemm_epl_kernel<<<NBLK, 512, 0, stream>>>(embb_sw, weight, queue, newrows, map,
                                              label, partials, posvals);
    reduce_kernel<<<2 * B, 256, 0, stream>>>(partials, negacc);
    loss_kernel<<<1, 256, 0, stream>>>(negacc, posvals, out);
}

// Round 4
// 434.349 us; speedup vs baseline: 1.2918x; 1.2918x over previous
//
#include <hip/hip_runtime.h>
#include <math.h>

#define B 256
#define F 512
#define C 100000
#define S_SCALE 64.0f
#define M_MARGIN 0.4f
#define K_VP 0.7f

#define BN 32
#define NTILES (C / BN)          // 3125 exact (C % 32 == 0): no tail guards
#define NT_TOT (2 * NTILES)      // 6250 flat tiles (src0: weight, src1: queue)
#define NBLK 256                 // persistent blocks, 1 per CU

typedef __bf16 bf16x8 __attribute__((ext_vector_type(8)));
typedef float  floatx4 __attribute__((ext_vector_type(4)));

// ---------- fused: emb = l2norm(input) -> swizzled bf16 A + newrows (exact fp32) ----------
// embb_sw layout: A-frag for (rowtile R, kstep ks) at 1KB region ((R*16+ks)*64 + lane)*16B,
// lane = (row&15) + 16*q, element j: k = ks*32 + q*8 + j.
__global__ void embnew_kernel(const float* __restrict__ input, const float* __restrict__ queue,
                              const int* __restrict__ label,
                              __bf16* __restrict__ embb_sw, float* __restrict__ newrows) {
    int i = blockIdx.x;
    int t = threadIdx.x;
    const float* x = input + (size_t)i * F;
    float x0 = x[t], x1 = x[t + 256];
    float p = x0 * x0 + x1 * x1;
    __shared__ float red[4];
    for (int off = 32; off > 0; off >>= 1) p += __shfl_down(p, off, 64);
    if ((t & 63) == 0) red[t >> 6] = p;
    __syncthreads();
    float tot = red[0] + red[1] + red[2] + red[3];
    float inv = 1.0f / fmaxf(sqrtf(tot), 1e-5f);
    float e0 = x0 * inv, e1 = x1 * inv;
    {
        int R = i >> 4, ln = i & 15;
        int k = t;
        embb_sw[(size_t)(((R * 16 + (k >> 5)) * 64 + ln + 16 * ((k & 31) >> 3)) * 8 + (k & 7))] = (__bf16)e0;
        k = t + 256;
        embb_sw[(size_t)(((R * 16 + (k >> 5)) * 64 + ln + 16 * ((k & 31) >> 3)) * 8 + (k & 7))] = (__bf16)e1;
    }
    int l = label[i];
    const float* qr = queue + (size_t)l * F;
    float q0 = qr[t], q1 = qr[t + 256];
    float pd = q0 * e0 + q1 * e1;
    __syncthreads();
    for (int off = 32; off > 0; off >>= 1) pd += __shfl_down(pd, off, 64);
    if ((t & 63) == 0) red[t >> 6] = pd;
    __syncthreads();
    float drift = red[0] + red[1] + red[2] + red[3];
    float f = drift / (1.0f + fabsf(drift));   // softsign
    float v0 = f * q0 + (1.0f - f) * e0;
    float v1 = f * q1 + (1.0f - f) * e1;
    float p2 = v0 * v0 + v1 * v1;
    __syncthreads();
    for (int off = 32; off > 0; off >>= 1) p2 += __shfl_down(p2, off, 64);
    if ((t & 63) == 0) red[t >> 6] = p2;
    __syncthreads();
    float tot2 = red[0] + red[1] + red[2] + red[3];
    float inv2 = 1.0f / fmaxf(sqrtf(tot2), 1e-12f);
    newrows[(size_t)i * F + t]       = v0 * inv2;
    newrows[(size_t)i * F + t + 256] = v1 * inv2;
}

// ---------- map[c] = -1 ----------
__global__ void init_kernel(int* __restrict__ map) {
    int idx = blockIdx.x * 256 + threadIdx.x;
    if (idx < C) map[idx] = -1;
}

// ---------- last-occurrence-wins scatter (numpy queue[label]=rows semantics) ----------
__global__ void scatter_kernel(const int* __restrict__ label, int* __restrict__ map) {
    atomicMax(&map[label[threadIdx.x]], (int)threadIdx.x);
}

// ---------- persistent pipelined bf16 MFMA GEMM + EPL epilogue ----------
// 256 blocks x 1024 threads (16 waves), 1 block/CU. Wave w owns rows 16w..16w+15, and its
// A fragments live PERMANENTLY in 64 VGPRs (aA[16]) -> zero A traffic in the main loop.
// Per tile: convert u[]->bf16 + lane-linear ds_write (vmcnt drains, covered by previous
// tile's MFMA+epilogue) | barrier | colinv | ISSUE next tile's 4 dwordx4 loads | MFMA
// 16 ks x 2 col-groups | barrier | epilogue (exp accumulated in ns0/ns1 registers across
// ALL tiles; shfl-reduce + one packed float4 store per block at the end).
// LDS B layout: 32 x 1KB regions; region (ks*2+ct), slot lane = (c&15)+16*q, elems
// k = ks*32+q*8+j. Staging wave w: ct=w&1, ks in {w>>1, (w>>1)+8} -> each thread owns ONE
// column (register sumsq), every ds_write_b128/ds_read_b128 lane-linear (conflict-free).
__global__ __launch_bounds__(1024, 4) void gemm_epl_kernel(
        const __bf16* __restrict__ embb_sw,
        const float* __restrict__ weight,
        const float* __restrict__ queue,
        const float* __restrict__ newrows,
        const int* __restrict__ map,
        const int* __restrict__ label,
        float* __restrict__ partials,
        float* __restrict__ posvals) {
    int tid = threadIdx.x;
    int w = tid >> 6;          // 0..15
    int l = tid & 63;
    int ln = l & 15;
    int q = l >> 4;
    int ctS = w & 1;           // staging col-group
    int ksA = w >> 1;          // staging ks pair {ksA, ksA+8}
    int cl = ctS * 16 + ln;    // the one column this thread stages

    __shared__ __align__(16) __bf16 bS[32 * 512];   // 32 KB frag-region buffer
    __shared__ float colpart_s[32][33];             // 32 partials per column, padded
    __shared__ float colinv_s[32];
    __shared__ int label_s[B];

    if (tid < B) label_s[tid] = label[tid];

    // resident A fragments: rows w*16..w*16+15, all 16 k-steps (64 VGPRs, loaded once)
    bf16x8 aA[16];
#pragma unroll
    for (int ks = 0; ks < 16; ++ks)
        aA[ks] = *(const bf16x8*)(embb_sw + ((size_t)((w * 16 + ks) * 64 + l) << 3));

    int ft0 = (int)(((long)blockIdx.x * NT_TOT) / NBLK);
    int ft1 = (int)(((long)(blockIdx.x + 1) * NT_TOT) / NBLK);

    float4 u[4];                                 // next tile's staged fp32 (in flight)
    float ns0[4] = {0.f, 0.f, 0.f, 0.f};         // per-row negative-exp accum, src0
    float ns1[4] = {0.f, 0.f, 0.f, 0.f};         // src1 (static arrays: rule-#20 safe)

    auto issue_loads = [&](int ft) {
        int s1 = (ft >= NTILES);
        int tile = ft - s1 * NTILES;
        int c = tile * BN + cl;
        const float* bp;
        if (!s1) bp = weight + (size_t)c * F;
        else {
            int mi = map[c];
            bp = (mi >= 0) ? newrows + (size_t)mi * F : queue + (size_t)c * F;
        }
        int k0 = ksA * 32 + q * 8;
        u[0] = *(const float4*)(bp + k0);
        u[1] = *(const float4*)(bp + k0 + 4);
        u[2] = *(const float4*)(bp + k0 + 256);      // (ksA+8)*32 + q*8
        u[3] = *(const float4*)(bp + k0 + 260);
    };

    issue_loads(ft0);   // first tile not overlapped

    for (int ft = ft0; ft < ft1; ++ft) {
        int s1 = (ft >= NTILES);
        int tile = ft - s1 * NTILES;
        int cbase = tile * BN;

        // ---- convert + lane-linear ds_write (vmcnt drains here, under prev-tile cover)
        {
            float4 u0 = u[0], u1 = u[1], u2 = u[2], u3 = u[3];
            float ss = u0.x * u0.x + u0.y * u0.y + u0.z * u0.z + u0.w * u0.w
                     + u1.x * u1.x + u1.y * u1.y + u1.z * u1.z + u1.w * u1.w
                     + u2.x * u2.x + u2.y * u2.y + u2.z * u2.z + u2.w * u2.w
                     + u3.x * u3.x + u3.y * u3.y + u3.z * u3.z + u3.w * u3.w;
            bf16x8 p0, p1;
            p0[0] = (__bf16)u0.x; p0[1] = (__bf16)u0.y; p0[2] = (__bf16)u0.z; p0[3] = (__bf16)u0.w;
            p0[4] = (__bf16)u1.x; p0[5] = (__bf16)u1.y; p0[6] = (__bf16)u1.z; p0[7] = (__bf16)u1.w;
            p1[0] = (__bf16)u2.x; p1[1] = (__bf16)u2.y; p1[2] = (__bf16)u2.z; p1[3] = (__bf16)u2.w;
            p1[4] = (__bf16)u3.x; p1[5] = (__bf16)u3.y; p1[6] = (__bf16)u3.z; p1[7] = (__bf16)u3.w;
            *(bf16x8*)&bS[(size_t)(((ksA * 2 + ctS) * 64 + l) * 8)]       = p0;
            *(bf16x8*)&bS[(size_t)((((ksA + 8) * 2 + ctS) * 64 + l) * 8)] = p1;
            colpart_s[cl][ksA * 4 + q] = ss;
        }
        __syncthreads();   // (A): bS + colpart ready

        if (tid < 32) {
            float s = 0.f;
#pragma unroll
            for (int p = 0; p < 32; ++p) s += colpart_s[tid][p];
            colinv_s[tid] = 1.0f / fmaxf(sqrtf(s), s1 ? 1e-12f : 1e-5f);
        }

        if (ft + 1 < ft1) issue_loads(ft + 1);   // HBM loads fly under the MFMA window

        // ---- MFMA: 16 ks x 2 col-groups, A from registers, B lane-linear from LDS
        floatx4 acc0 = (floatx4){0.f, 0.f, 0.f, 0.f};
        floatx4 acc1 = (floatx4){0.f, 0.f, 0.f, 0.f};
#pragma unroll
        for (int ks = 0; ks < 16; ++ks) {
            bf16x8 b0 = *(const bf16x8*)&bS[(size_t)(((ks * 2 + 0) * 64 + l) * 8)];
            bf16x8 b1 = *(const bf16x8*)&bS[(size_t)(((ks * 2 + 1) * 64 + l) * 8)];
            acc0 = __builtin_amdgcn_mfma_f32_16x16x32_bf16(aA[ks], b0, acc0, 0, 0, 0);
            acc1 = __builtin_amdgcn_mfma_f32_16x16x32_bf16(aA[ks], b1, acc1, 0, 0, 0);
        }
        __syncthreads();   // (B): colinv visible; bS reads done (next write is after (A))

        // ---- epilogue: accumulate into per-src static register arrays (uniform branch)
#define EPL_BODY(NS)                                                          \
        _Pragma("unroll")                                                     \
        for (int r = 0; r < 4; ++r) {                                         \
            int row = w * 16 + q * 4 + r;                                     \
            int lab = label_s[row];                                           \
            float v0 = acc0[r] * colinv_s[ln];                                \
            float v1 = acc1[r] * colinv_s[16 + ln];                           \
            if (cbase + ln == lab) posvals[s1 * B + row] = v0;                \
            else NS[r] += __expf(S_SCALE * v0);                               \
            if (cbase + 16 + ln == lab) posvals[s1 * B + row] = v1;           \
            else NS[r] += __expf(S_SCALE * v1);                               \
        }
        if (!s1) { EPL_BODY(ns0) } else { EPL_BODY(ns1) }
#undef EPL_BODY
    }

    // ---- block-end: reduce ns over the 16-lane col group, one packed store per row
#pragma unroll
    for (int r = 0; r < 4; ++r) {
#pragma unroll
        for (int off = 1; off <= 8; off <<= 1) {
            ns0[r] += __shfl_xor(ns0[r], off, 64);
            ns1[r] += __shfl_xor(ns1[r], off, 64);
        }
    }
    if (ln == 0) {
        int rb = w * 16 + q * 4;
        float4 a = make_float4(ns0[0], ns0[1], ns0[2], ns0[3]);
        float4 b = make_float4(ns1[0], ns1[1], ns1[2], ns1[3]);
        *(float4*)&partials[(size_t)blockIdx.x * 512 + rb]       = a;   // src0 rows
        *(float4*)&partials[(size_t)blockIdx.x * 512 + 256 + rb] = b;   // src1 rows
    }
}

// ---------- reduce partials across blocks: negacc[j] = sum_bx partials[bx*512 + j] ----------
__global__ void reduce_kernel(const float* __restrict__ partials, float* __restrict__ negacc) {
    int j = blockIdx.x * 256 + threadIdx.x;   // 0..511
    float s = 0.f;
    for (int bx = 0; bx < NBLK; ++bx) s += partials[(size_t)bx * 512 + j];
    negacc[j] = s;
}

// ---------- final EPL loss ----------
__global__ void loss_kernel(const float* __restrict__ negacc, const float* __restrict__ posvals,
                            float* __restrict__ out) {
    int t = threadIdx.x;  // 256
    float l1 = log1pf(negacc[t] * __expf(-S_SCALE * (posvals[t] - M_MARGIN)));
    float l2 = log1pf(negacc[B + t] * __expf(-S_SCALE * (1.0f - K_VP) * posvals[B + t]));
    float p = l1 + l2;
    __shared__ float red[4];
    for (int off = 32; off > 0; off >>= 1) p += __shfl_down(p, off, 64);
    if ((t & 63) == 0) red[t >> 6] = p;
    __syncthreads();
    if (t == 0) out[0] = (red[0] + red[1] + red[2] + red[3]) / (2.0f * B);
}

extern "C" void kernel_launch(void* const* d_in, const int* in_sizes, int n_in,
                              void* d_out, int out_size, void* d_ws, size_t ws_size,
                              hipStream_t stream) {
    const float* input  = (const float*)d_in[0];
    const float* weight = (const float*)d_in[1];
    const float* queue  = (const float*)d_in[2];
    const int*   label  = (const int*)d_in[3];
    float* out = (float*)d_out;

    char* ws = (char*)d_ws;
    __bf16* embb_sw  = (__bf16*)(ws);                         // 256 KB
    float*  newrows  = (float*)(ws + (256 << 10));            // 512 KB
    float*  negacc   = (float*)(ws + (768 << 10));            // 2 KB
    float*  posvals  = (float*)(ws + (768 << 10) + 2048);     // 2 KB
    int*    map      = (int*)  (ws + (768 << 10) + 4096);     // 400 KB
    float*  partials = (float*)(ws + (1200 << 10));           // 256*512*4 = 512 KB

    init_kernel<<<(C + 255) / 256, 256, 0, stream>>>(map);
    scatter_kernel<<<1, B, 0, stream>>>(label, map);
    embnew_kernel<<<B, 256, 0, stream>>>(input, queue, label, embb_sw, newrows);
    gemm_epl_kernel<<<NBLK, 1024, 0, stream>>>(embb_sw, weight, queue, newrows, map,
                                               label, partials, posvals);
    reduce_kernel<<<2, 256, 0, stream>>>(partials, negacc);
    loss_kernel<<<1, 256, 0, stream>>>(negacc, posvals, out);
}